// Round 11
// baseline (155.828 us; speedup 1.0000x reference)
//
#include <hip/hip_runtime.h>
#include <hip/hip_fp16.h>
#include <math.h>

__device__ __forceinline__ int refl256(int t) {
    t = t < 0 ? -t : t;
    return t > 255 ? 510 - t : t;
}

__device__ __forceinline__ void unpack4h(uint2 u, float* g4) {
    __half2 h01 = *(__half2*)&u.x, h23 = *(__half2*)&u.y;
    g4[0] = __low2float(h01); g4[1] = __high2float(h01);
    g4[2] = __low2float(h23); g4[3] = __high2float(h23);
}
__device__ __forceinline__ void unpack8h(uint4 u, float* k4, float* v4) {
    __half2 a = *(__half2*)&u.x, b = *(__half2*)&u.y;
    __half2 c = *(__half2*)&u.z, d = *(__half2*)&u.w;
    k4[0] = __low2float(a); k4[1] = __high2float(a);
    k4[2] = __low2float(b); k4[3] = __high2float(b);
    v4[0] = __low2float(c); v4[1] = __high2float(c);
    v4[2] = __low2float(d); v4[3] = __high2float(d);
}

// ---------------- stage 1: p=1, NH=6, 2x2 quad + 3-way head split ----------
// Thread = 2x2 pixel quad; 16 shared k/v projection positions serve 4 pixels.
// threadIdx.y = head-group (2 heads each); groups 1,2 -> LDS, group 0 combines.
__global__ __launch_bounds__(384)
void attn_p1q3(const float* __restrict__ x, const float* __restrict__ w,
               const float* __restrict__ bq, const float* __restrict__ hw,
               float* __restrict__ out, float* __restrict__ pmax)
{
    const int slot = threadIdx.x;                      // 0..127
    const int hg = __builtin_amdgcn_readfirstlane((int)threadIdx.y);  // 0,1,2
    int t2 = blockIdx.x * 128 + slot;                  // 65536 quads
    int qx = t2 & 127, qy = (t2 >> 7) & 127, bb = t2 >> 14;
    int x0 = qx * 2, y0 = qy * 2;
    const float* xb = x + bb * 196608;
    int rs[4], cs[4];
#pragma unroll
    for (int d = 0; d < 4; ++d) {
        rs[d] = refl256(y0 + d - 1) << 8;
        cs[d] = refl256(x0 + d - 1);
    }
    float xw[4][4][3];
#pragma unroll
    for (int dr = 0; dr < 4; ++dr)
#pragma unroll
        for (int dc = 0; dc < 4; ++dc)
#pragma unroll
            for (int c = 0; c < 3; ++c)
                xw[dr][dc][c] = xb[c * 65536 + rs[dr] + cs[dc]];

    // fused batch-max partial (own pixels = rows 1,2 x cols 1,2)
    {
        float bm = 0.f;
#pragma unroll
        for (int c = 0; c < 3; ++c) {
            bm = fmaxf(bm, fmaxf(xw[1][1][c], xw[1][2][c]));
            bm = fmaxf(bm, fmaxf(xw[2][1][c], xw[2][2][c]));
        }
#pragma unroll
        for (int off = 32; off > 0; off >>= 1)
            bm = fmaxf(bm, __shfl_down(bm, off, 64));
        __shared__ float sm[6];
        int flat = threadIdx.y * 128 + slot;
        if ((flat & 63) == 0) sm[flat >> 6] = bm;
        __syncthreads();
        if (flat == 0) {
            float v = sm[0];
#pragma unroll
            for (int k = 1; k < 6; ++k) v = fmaxf(v, sm[k]);
            pmax[blockIdx.x] = v;
        }
    }

    float ov[2][2][3];
#pragma unroll
    for (int py = 0; py < 2; ++py)
#pragma unroll
        for (int px = 0; px < 2; ++px)
#pragma unroll
            for (int c = 0; c < 3; ++c) ov[py][px][c] = 0.f;
    const float scl = 0.57735026919f;  // 1/sqrt(3); bias == 1 for p=1
#pragma unroll 1
    for (int hi = 0; hi < 2; ++hi) {
        int h = hg * 2 + hi;
        float hwh = hw[h];
#pragma unroll
        for (int cc = 0; cc < 3; ++cc) {
            int oq = 9 * h + cc, ok = oq + 3, oV = oq + 6;
            float wq0 = w[oq * 3], wq1 = w[oq * 3 + 1], wq2 = w[oq * 3 + 2];
            float wk0 = w[ok * 3], wk1 = w[ok * 3 + 1], wk2 = w[ok * 3 + 2];
            float wv0 = w[oV * 3], wv1 = w[oV * 3 + 1], wv2 = w[oV * 3 + 2];
            float bqq = bq[oq], bk = bq[ok], bv = bq[oV];
            float kp[16], vp[16];
#pragma unroll
            for (int pos = 0; pos < 16; ++pos) {
                const float* xv = xw[pos >> 2][pos & 3];
                kp[pos] = fmaf(xv[0], wk0, fmaf(xv[1], wk1, fmaf(xv[2], wk2, bk)));
                vp[pos] = fmaf(xv[0], wv0, fmaf(xv[1], wv1, fmaf(xv[2], wv2, bv)));
            }
#pragma unroll
            for (int py = 0; py < 2; ++py)
#pragma unroll
                for (int px = 0; px < 2; ++px) {
                    const float* xc = xw[1 + py][1 + px];
                    float q = fmaf(xc[0], wq0, fmaf(xc[1], wq1, fmaf(xc[2], wq2, bqq))) * scl;
                    float se = 0.f, ac = 0.f;
#pragma unroll
                    for (int dr = 0; dr < 3; ++dr)
#pragma unroll
                        for (int dc = 0; dc < 3; ++dc) {
                            int pos = (py + dr) * 4 + (px + dc);
                            float e0 = __expf(q * kp[pos]);
                            se += e0; ac = fmaf(e0, vp[pos], ac);
                        }
                    ov[py][px][cc] = fmaf(hwh, ac / se, ov[py][px][cc]);
                }
        }
    }
    __shared__ float s_part[2][128][12];
    if (hg > 0) {
#pragma unroll
        for (int py = 0; py < 2; ++py)
#pragma unroll
            for (int px = 0; px < 2; ++px)
#pragma unroll
                for (int cc = 0; cc < 3; ++cc)
                    s_part[hg - 1][slot][(py * 2 + px) * 3 + cc] = ov[py][px][cc];
    }
    __syncthreads();
    if (hg == 0) {
        float* ob = out + bb * 196608;
#pragma unroll
        for (int cc = 0; cc < 3; ++cc)
#pragma unroll
            for (int py = 0; py < 2; ++py) {
                float2 o2;
                int e0 = (py * 2 + 0) * 3 + cc, e1 = (py * 2 + 1) * 3 + cc;
                o2.x = ov[py][0][cc] + s_part[0][slot][e0] + s_part[1][slot][e0];
                o2.y = ov[py][1][cc] + s_part[0][slot][e1] + s_part[1][slot][e1];
                *(float2*)(ob + cc * 65536 + ((y0 + py) << 8) + x0) = o2;
            }
    }
}

// ---------------- two-phase attention for p=2 / p=3, fp16 KV ----------------
// Phase 1: lane = tile (direct gather), wave = uniform stride over slot tasks.
// q-slots -> uint2 kvq[s*T4+t]; interleaved k|v slots -> uint4 kvv[s*T4+t].
template<int P, int NH, int NWIN, int OFS, int GSU, int NCH>
__global__ __launch_bounds__(64 * NCH)
void proj4_pk(const float* __restrict__ x, const float* __restrict__ w,
              const float* __restrict__ bq,
              uint2* __restrict__ kvq, uint4* __restrict__ kvv)
{
    constexpr int PP = P * P, L = 3 * PP, NGP = PP / GSU;
    constexpr int QS = NH * 3 * NGP, TOT = 2 * QS;
    constexpr int NT = NWIN + 2, T4 = 4 * NT * NT;
    int t = blockIdx.x * 64 + threadIdx.x;
    if (t >= T4) return;
    const int wvi = __builtin_amdgcn_readfirstlane((int)threadIdx.y);
    int bb = t / (NT * NT), rr = t - bb * NT * NT;
    int ty = rr / NT, tx = rr - ty * NT;
    const float* xb = x + bb * 196608;
    float xw[L];
#pragma unroll
    for (int i = 0; i < P; ++i) {
        int pr = refl256(ty * P + i - OFS) << 8;
#pragma unroll
        for (int j = 0; j < P; ++j) {
            int pc = refl256(tx * P + j - OFS);
#pragma unroll
            for (int c = 0; c < 3; ++c)
                xw[c * PP + i * P + j] = xb[c * 65536 + pr + pc];
        }
    }
#pragma unroll 1
    for (int s = wvi; s < TOT; s += NCH) {
        int sq = (s < QS) ? s : s - QS;
        int h = sq / (3 * NGP);
        int rem = sq - h * (3 * NGP);
        int c = rem / NGP, u = rem - c * NGP;
        if (s < QS) {
            int ob = ((h * 3 + 0) * 3 + c) * PP + u * GSU;
            float acc[GSU];
#pragma unroll
            for (int e = 0; e < GSU; ++e) acc[e] = bq[ob + e];
#pragma unroll
            for (int l = 0; l < L; ++l) {
                float xv = xw[l];
#pragma unroll
                for (int e = 0; e < GSU; ++e)
                    acc[e] = fmaf(xv, w[(ob + e) * L + l], acc[e]);
            }
            __half2 a01 = __floats2half2_rn(acc[0], acc[1]);
            __half2 a23 = __floats2half2_rn(GSU > 2 ? acc[2] : 0.f,
                                            GSU > 3 ? acc[GSU - 1] : 0.f);
            uint2 o;
            o.x = *(unsigned*)&a01;
            o.y = *(unsigned*)&a23;
            kvq[(size_t)sq * T4 + t] = o;
        } else {
            int okb = ((h * 3 + 1) * 3 + c) * PP + u * GSU;
            int ovb = ((h * 3 + 2) * 3 + c) * PP + u * GSU;
            float ak[GSU], av[GSU];
#pragma unroll
            for (int e = 0; e < GSU; ++e) { ak[e] = bq[okb + e]; av[e] = bq[ovb + e]; }
#pragma unroll
            for (int l = 0; l < L; ++l) {
                float xv = xw[l];
#pragma unroll
                for (int e = 0; e < GSU; ++e) {
                    ak[e] = fmaf(xv, w[(okb + e) * L + l], ak[e]);
                    av[e] = fmaf(xv, w[(ovb + e) * L + l], av[e]);
                }
            }
            __half2 k01 = __floats2half2_rn(ak[0], ak[1]);
            __half2 k23 = __floats2half2_rn(GSU > 2 ? ak[2] : 0.f,
                                            GSU > 3 ? ak[GSU - 1] : 0.f);
            __half2 v01 = __floats2half2_rn(av[0], av[1]);
            __half2 v23 = __floats2half2_rn(GSU > 2 ? av[2] : 0.f,
                                            GSU > 3 ? av[GSU - 1] : 0.f);
            uint4 o;
            o.x = *(unsigned*)&k01;
            o.y = *(unsigned*)&k23;
            o.z = *(unsigned*)&v01;
            o.w = *(unsigned*)&v23;
            kvv[(size_t)sq * T4 + t] = o;
        }
    }
}

// Phase 2: single-pass unnormalized softmax; one 16B load gives k AND v.
template<int P, int NH, int NWIN, int OFS, int GSU, int HPT>
__global__ __launch_bounds__(256)
void attn4_pk(const uint2* __restrict__ kvq, const uint4* __restrict__ kvv,
              const float* __restrict__ hw, float* __restrict__ out)
{
    constexpr int PP = P * P, NGP = PP / GSU;
    constexpr int NT = NWIN + 2, T4 = 4 * NT * NT, PAD = OFS - P;
    constexpr float SCL = (P == 2) ? 0.28867513459481287f : 0.19245008972987526f;
    constexpr float DD  = (P == 2) ? 0.6065306597126334f : 0.7165313105737893f; // exp(-1/P)
    float dpw[2 * P - 1];
    dpw[0] = 1.f;
#pragma unroll
    for (int k = 1; k < 2 * P - 1; ++k) dpw[k] = dpw[k - 1] * DD;

    const int slot = threadIdx.x;                       // 0..127
    const int hg = __builtin_amdgcn_readfirstlane((int)threadIdx.y);
    int wlin = blockIdx.x * 128 + slot;
    const bool active = wlin < 4 * NWIN * NWIN;
    int wsafe = active ? wlin : 0;
    int c = blockIdx.y;
    int bb = wsafe / (NWIN * NWIN); int rr = wsafe - bb * (NWIN * NWIN);
    int yy = rr / NWIN, xx = rr - yy * NWIN;
    int tbase = bb * NT * NT + yy * NT + xx;
    int tn[9];
#pragma unroll
    for (int di = 0; di < 3; ++di)
#pragma unroll
        for (int dj = 0; dj < 3; ++dj) tn[di * 3 + dj] = tbase + di * NT + dj;
    float oa[PP];
#pragma unroll
    for (int e = 0; e < PP; ++e) oa[e] = 0.f;
#pragma unroll 1
    for (int hi = 0; hi < HPT; ++hi) {
        int h = hg * HPT + hi;
        int sb = (h * 3 + c) * NGP;
        float q[PP];
#pragma unroll
        for (int u = 0; u < NGP; ++u) {
            float g4[4];
            unpack4h(kvq[(size_t)(sb + u) * T4 + tn[4]], g4);
#pragma unroll
            for (int e = 0; e < GSU; ++e) q[u * GSU + e] = g4[e];
        }
        float se = 0.f;
        float tmp[PP];
#pragma unroll
        for (int e = 0; e < PP; ++e) tmp[e] = 0.f;
#pragma unroll
        for (int j = 0; j < 9; ++j) {
            int di = j / 3, dj = j - di * 3;
            float vreg[PP];
            float s = 0.f;
#pragma unroll
            for (int u = 0; u < NGP; ++u) {
                float k4[4], v4[4];
                unpack8h(kvv[(size_t)(sb + u) * T4 + tn[j]], k4, v4);
#pragma unroll
                for (int e = 0; e < GSU; ++e) {
                    int Pp = u * GSU + e;
                    int i = Pp / P, jj = Pp - i * P;
                    int er = (di == 0) ? (P - 1 - i) : (di == 2 ? i : 0);
                    int ec = (dj == 0) ? (P - 1 - jj) : (dj == 2 ? jj : 0);
                    s = fmaf(q[Pp] * k4[e], dpw[er + ec], s);
                    vreg[Pp] = v4[e];
                }
            }
            float e2 = __expf(s * SCL);
            se += e2;
#pragma unroll
            for (int e = 0; e < PP; ++e) tmp[e] = fmaf(e2, vreg[e], tmp[e]);
        }
        float f = hw[h] / se;
#pragma unroll
        for (int e = 0; e < PP; ++e) oa[e] = fmaf(f, tmp[e], oa[e]);
    }
    __shared__ float s_part[128][PP];
    if (hg == 1) {
#pragma unroll
        for (int e = 0; e < PP; ++e) s_part[slot][e] = oa[e];
    }
    __syncthreads();
    if (hg == 0 && active) {
        float* ob = out + (bb * 3 + c) * 65536;
#pragma unroll
        for (int i = 0; i < P; ++i) {
            int r = yy * P + i - PAD;
            if (PAD && r < 0) continue;
#pragma unroll
            for (int jj = 0; jj < P; ++jj) {
                int col = xx * P + jj - PAD;
                if (PAD && col < 0) continue;
                int e = i * P + jj;
                ob[(r << 8) + col] = oa[e] + s_part[slot][e];
            }
        }
    }
}

// -------- conv0 (5x5, 9->3, pad 2) + final, source-split over y ------------
__global__ __launch_bounds__(384)
void conv_finalv3(const float* __restrict__ x, const float* __restrict__ x9,
                  const float* __restrict__ x6, const float* __restrict__ x3,
                  const float* __restrict__ cw, const float* __restrict__ cb,
                  const float* __restrict__ pmax, float* __restrict__ out)
{
    const int slot = threadIdx.x;                       // 0..127
    const int src = __builtin_amdgcn_readfirstlane((int)threadIdx.y);  // 0,1,2
    int bb = blockIdx.x >> 8;                           // 1024 blocks, 256/batch
    __shared__ float s_g;
    {
        int flat = threadIdx.y * 128 + slot;
        if (flat < 32) {                                // 128 partials per batch
            const float* pm = pmax + bb * 128 + flat * 4;
            float v = fmaxf(fmaxf(pm[0], pm[1]), fmaxf(pm[2], pm[3]));
#pragma unroll
            for (int off = 16; off > 0; off >>= 1)
                v = fmaxf(v, __shfl_down(v, off, 64));
            if (flat == 0) s_g = v;
        }
    }
    int pair = (blockIdx.x & 255) * 128 + slot;         // within batch
    int xp = (pair & 127) << 1, r = pair >> 7;
    float a[3][2];
#pragma unroll
    for (int oc = 0; oc < 3; ++oc) { a[oc][0] = 0.f; a[oc][1] = 0.f; }
    const float* bp = (src == 0 ? x9 : (src == 1 ? x6 : x3)) + bb * 196608;
#pragma unroll 1
    for (int c2 = 0; c2 < 3; ++c2) {
        const float* pl = bp + c2 * 65536;
        const float* wp = cw + (src * 3 + c2) * 25;     // wave-uniform -> s_load
#pragma unroll
        for (int ky = 0; ky < 5; ++ky) {
            int rr = r + ky - 2;
            if ((unsigned)rr >= 256u) continue;
            const float* row = pl + (rr << 8);
            float2 va = (xp >= 2) ? *(const float2*)(row + xp - 2)
                                  : make_float2(0.f, 0.f);
            float2 vb = *(const float2*)(row + xp);
            float2 vc = (xp + 2 < 256) ? *(const float2*)(row + xp + 2)
                                       : make_float2(0.f, 0.f);
            float cv[6] = {va.x, va.y, vb.x, vb.y, vc.x, vc.y};
#pragma unroll
            for (int kx = 0; kx < 5; ++kx) {
                float w0 = wp[ky * 5 + kx];
                float w1 = wp[225 + ky * 5 + kx];
                float w2 = wp[450 + ky * 5 + kx];
                float v0 = cv[kx], v1 = cv[kx + 1];
                a[0][0] = fmaf(v0, w0, a[0][0]); a[0][1] = fmaf(v1, w0, a[0][1]);
                a[1][0] = fmaf(v0, w1, a[1][0]); a[1][1] = fmaf(v1, w1, a[1][1]);
                a[2][0] = fmaf(v0, w2, a[2][0]); a[2][1] = fmaf(v1, w2, a[2][1]);
            }
        }
    }
    __shared__ float s_part[2][128][6];
    if (src > 0) {
#pragma unroll
        for (int oc = 0; oc < 3; ++oc) {
            s_part[src - 1][slot][oc * 2]     = a[oc][0];
            s_part[src - 1][slot][oc * 2 + 1] = a[oc][1];
        }
    }
    __syncthreads();
    if (src == 0) {
        float g = s_g;
        int pix = (r << 8) + xp;
        const float* xb = x + bb * 196608;
        float* ob = out + bb * 196608;
#pragma unroll
        for (int oc = 0; oc < 3; ++oc) {
            float a0 = a[oc][0] + s_part[0][slot][oc * 2] + s_part[1][slot][oc * 2] + cb[oc];
            float a1 = a[oc][1] + s_part[0][slot][oc * 2 + 1] + s_part[1][slot][oc * 2 + 1] + cb[oc];
            float2 xv = *(const float2*)(xb + oc * 65536 + pix);
            float2 o2;
            float x0;
            x0 = fmaxf(a0, 0.f); o2.x = fmaxf(xv.x * x0 + g - x0, 0.f);
            x0 = fmaxf(a1, 0.f); o2.y = fmaxf(xv.y * x0 + g - x0, 0.f);
            *(float2*)(ob + oc * 65536 + pix) = o2;
        }
    }
}

extern "C" void kernel_launch(void* const* d_in, const int* in_sizes, int n_in,
                              void* d_out, int out_size, void* d_ws, size_t ws_size,
                              hipStream_t stream)
{
    const float* x   = (const float*)d_in[0];
    const float* w3  = (const float*)d_in[1];
    const float* b3  = (const float*)d_in[2];
    const float* hw3 = (const float*)d_in[3];
    const float* w6  = (const float*)d_in[4];
    const float* b6  = (const float*)d_in[5];
    const float* hw6 = (const float*)d_in[6];
    const float* w9  = (const float*)d_in[7];
    const float* b9  = (const float*)d_in[8];
    const float* hw9 = (const float*)d_in[9];
    const float* cw  = (const float*)d_in[10];
    const float* cb  = (const float*)d_in[11];

    float* ws   = (float*)d_ws;
    float* x3b  = ws;                     // 786432 floats
    float* x6b  = ws + 786432;            // 786432
    float* x9b  = ws + 1572864;           // 786432
    float* pmax = ws + 2359296;           // 512
    uint2* kvq  = (uint2*)(ws + 2360320); // q slots: <= 12*67600*8 B = 6.5 MB
    uint4* kvv  = (uint4*)(ws + 3982720); // k|v slots: <= 12*67600*16 B = 13 MB
    float* out  = (float*)d_out;

    // stage 1 (p=1), 2x2 quads, 3-way head split, + fused batch-max partials
    attn_p1q3<<<512, dim3(128, 3), 0, stream>>>(x, w3, b3, hw3, x3b, pmax);

    // stage 2: p=2, NH=4, NWIN=128, OFS=2, GSU=4 (NGP=1), NCH=6
    proj4_pk<2, 4, 128, 2, 4, 6><<<1057, dim3(64, 6), 0, stream>>>(x3b, w6, b6, kvq, kvv);
    attn4_pk<2, 4, 128, 2, 4, 2><<<dim3(512, 3), dim3(128, 2), 0, stream>>>(kvq, kvv, hw6, x6b);
    // stage 3: p=3, NH=2, NWIN=86, OFS=5, GSU=3 (NGP=3), NCH=9
    proj4_pk<3, 2, 86, 5, 3, 9><<<484, dim3(64, 9), 0, stream>>>(x6b, w9, b9, kvq, kvv);
    attn4_pk<3, 2, 86, 5, 3, 1><<<dim3(232, 3), dim3(128, 2), 0, stream>>>(kvq, kvv, hw9, x9b);

    conv_finalv3<<<1024, dim3(128, 3), 0, stream>>>(x, x9b, x6b, x3b, cw, cb, pmax, out);
}

// Round 12
// 150.553 us; speedup vs baseline: 1.0350x; 1.0350x over previous
//
#include <hip/hip_runtime.h>
#include <hip/hip_fp16.h>
#include <math.h>

__device__ __forceinline__ int refl256(int t) {
    t = t < 0 ? -t : t;
    return t > 255 ? 510 - t : t;
}
__device__ __forceinline__ float fastrcp(float x) {
    return __builtin_amdgcn_rcpf(x);   // v_rcp_f32, ~1e-6 rel err
}

__device__ __forceinline__ void unpack4h(uint2 u, float* g4) {
    __half2 h01 = *(__half2*)&u.x, h23 = *(__half2*)&u.y;
    g4[0] = __low2float(h01); g4[1] = __high2float(h01);
    g4[2] = __low2float(h23); g4[3] = __high2float(h23);
}
__device__ __forceinline__ void unpack8h(uint4 u, float* k4, float* v4) {
    __half2 a = *(__half2*)&u.x, b = *(__half2*)&u.y;
    __half2 c = *(__half2*)&u.z, d = *(__half2*)&u.w;
    k4[0] = __low2float(a); k4[1] = __high2float(a);
    k4[2] = __low2float(b); k4[3] = __high2float(b);
    v4[0] = __low2float(c); v4[1] = __high2float(c);
    v4[2] = __low2float(d); v4[3] = __high2float(d);
}

// ---------------- stage 1: p=1, NH=6, 2x2 quad + 2-way head split ----------
// Thread = 2x2 pixel quad; 16 shared k/v projection positions serve 4 pixels.
// (3-way split regressed in R11: redundant neighborhood loads outweigh the
//  shorter chain. Keep 2-way.)
__global__ __launch_bounds__(256)
void attn_p1q(const float* __restrict__ x, const float* __restrict__ w,
              const float* __restrict__ bq, const float* __restrict__ hw,
              float* __restrict__ out, float* __restrict__ pmax)
{
    const int slot = threadIdx.x;                      // 0..127
    const int hg = __builtin_amdgcn_readfirstlane((int)threadIdx.y);
    int t2 = blockIdx.x * 128 + slot;                  // 65536 quads
    int qx = t2 & 127, qy = (t2 >> 7) & 127, bb = t2 >> 14;
    int x0 = qx * 2, y0 = qy * 2;
    const float* xb = x + bb * 196608;
    int rs[4], cs[4];
#pragma unroll
    for (int d = 0; d < 4; ++d) {
        rs[d] = refl256(y0 + d - 1) << 8;
        cs[d] = refl256(x0 + d - 1);
    }
    float xw[4][4][3];
#pragma unroll
    for (int dr = 0; dr < 4; ++dr)
#pragma unroll
        for (int dc = 0; dc < 4; ++dc)
#pragma unroll
            for (int c = 0; c < 3; ++c)
                xw[dr][dc][c] = xb[c * 65536 + rs[dr] + cs[dc]];

    // fused batch-max partial (own pixels = rows 1,2 x cols 1,2)
    {
        float bm = 0.f;
#pragma unroll
        for (int c = 0; c < 3; ++c) {
            bm = fmaxf(bm, fmaxf(xw[1][1][c], xw[1][2][c]));
            bm = fmaxf(bm, fmaxf(xw[2][1][c], xw[2][2][c]));
        }
#pragma unroll
        for (int off = 32; off > 0; off >>= 1)
            bm = fmaxf(bm, __shfl_down(bm, off, 64));
        __shared__ float sm[4];
        int flat = threadIdx.y * 128 + slot;
        if ((flat & 63) == 0) sm[flat >> 6] = bm;
        __syncthreads();
        if (flat == 0)
            pmax[blockIdx.x] = fmaxf(fmaxf(sm[0], sm[1]), fmaxf(sm[2], sm[3]));
    }

    float ov[2][2][3];
#pragma unroll
    for (int py = 0; py < 2; ++py)
#pragma unroll
        for (int px = 0; px < 2; ++px)
#pragma unroll
            for (int c = 0; c < 3; ++c) ov[py][px][c] = 0.f;
    const float scl = 0.57735026919f;  // 1/sqrt(3); bias == 1 for p=1
#pragma unroll 1
    for (int hi = 0; hi < 3; ++hi) {
        int h = hg * 3 + hi;
        float hwh = hw[h];
#pragma unroll
        for (int cc = 0; cc < 3; ++cc) {
            int oq = 9 * h + cc, ok = oq + 3, oV = oq + 6;
            float wq0 = w[oq * 3], wq1 = w[oq * 3 + 1], wq2 = w[oq * 3 + 2];
            float wk0 = w[ok * 3], wk1 = w[ok * 3 + 1], wk2 = w[ok * 3 + 2];
            float wv0 = w[oV * 3], wv1 = w[oV * 3 + 1], wv2 = w[oV * 3 + 2];
            float bqq = bq[oq], bk = bq[ok], bv = bq[oV];
            float kp[16], vp[16];
#pragma unroll
            for (int pos = 0; pos < 16; ++pos) {
                const float* xv = xw[pos >> 2][pos & 3];
                kp[pos] = fmaf(xv[0], wk0, fmaf(xv[1], wk1, fmaf(xv[2], wk2, bk)));
                vp[pos] = fmaf(xv[0], wv0, fmaf(xv[1], wv1, fmaf(xv[2], wv2, bv)));
            }
#pragma unroll
            for (int py = 0; py < 2; ++py)
#pragma unroll
                for (int px = 0; px < 2; ++px) {
                    const float* xc = xw[1 + py][1 + px];
                    float q = fmaf(xc[0], wq0, fmaf(xc[1], wq1, fmaf(xc[2], wq2, bqq))) * scl;
                    float se = 0.f, ac = 0.f;
#pragma unroll
                    for (int dr = 0; dr < 3; ++dr)
#pragma unroll
                        for (int dc = 0; dc < 3; ++dc) {
                            int pos = (py + dr) * 4 + (px + dc);
                            float e0 = __expf(q * kp[pos]);
                            se += e0; ac = fmaf(e0, vp[pos], ac);
                        }
                    ov[py][px][cc] = fmaf(hwh * ac, fastrcp(se), ov[py][px][cc]);
                }
        }
    }
    __shared__ float s_part[128][12];
    if (hg == 1) {
#pragma unroll
        for (int py = 0; py < 2; ++py)
#pragma unroll
            for (int px = 0; px < 2; ++px)
#pragma unroll
                for (int cc = 0; cc < 3; ++cc)
                    s_part[slot][(py * 2 + px) * 3 + cc] = ov[py][px][cc];
    }
    __syncthreads();
    if (hg == 0) {
        float* ob = out + bb * 196608;
#pragma unroll
        for (int cc = 0; cc < 3; ++cc)
#pragma unroll
            for (int py = 0; py < 2; ++py) {
                float2 o2;
                o2.x = ov[py][0][cc] + s_part[slot][(py * 2 + 0) * 3 + cc];
                o2.y = ov[py][1][cc] + s_part[slot][(py * 2 + 1) * 3 + cc];
                *(float2*)(ob + cc * 65536 + ((y0 + py) << 8) + x0) = o2;
            }
    }
}

// ---------------- two-phase attention for p=2 / p=3, fp16 KV ----------------
template<int P, int NH, int NWIN, int OFS, int GSU, int NCH>
__global__ __launch_bounds__(64 * NCH)
void proj4_pk(const float* __restrict__ x, const float* __restrict__ w,
              const float* __restrict__ bq,
              uint2* __restrict__ kvq, uint4* __restrict__ kvv)
{
    constexpr int PP = P * P, L = 3 * PP, NGP = PP / GSU;
    constexpr int QS = NH * 3 * NGP, TOT = 2 * QS;
    constexpr int NT = NWIN + 2, T4 = 4 * NT * NT;
    int t = blockIdx.x * 64 + threadIdx.x;
    if (t >= T4) return;
    const int wvi = __builtin_amdgcn_readfirstlane((int)threadIdx.y);
    int bb = t / (NT * NT), rr = t - bb * NT * NT;
    int ty = rr / NT, tx = rr - ty * NT;
    const float* xb = x + bb * 196608;
    float xw[L];
#pragma unroll
    for (int i = 0; i < P; ++i) {
        int pr = refl256(ty * P + i - OFS) << 8;
#pragma unroll
        for (int j = 0; j < P; ++j) {
            int pc = refl256(tx * P + j - OFS);
#pragma unroll
            for (int c = 0; c < 3; ++c)
                xw[c * PP + i * P + j] = xb[c * 65536 + pr + pc];
        }
    }
#pragma unroll 1
    for (int s = wvi; s < TOT; s += NCH) {
        int sq = (s < QS) ? s : s - QS;
        int h = sq / (3 * NGP);
        int rem = sq - h * (3 * NGP);
        int c = rem / NGP, u = rem - c * NGP;
        if (s < QS) {
            int ob = ((h * 3 + 0) * 3 + c) * PP + u * GSU;
            float acc[GSU];
#pragma unroll
            for (int e = 0; e < GSU; ++e) acc[e] = bq[ob + e];
#pragma unroll
            for (int l = 0; l < L; ++l) {
                float xv = xw[l];
#pragma unroll
                for (int e = 0; e < GSU; ++e)
                    acc[e] = fmaf(xv, w[(ob + e) * L + l], acc[e]);
            }
            __half2 a01 = __floats2half2_rn(acc[0], acc[1]);
            __half2 a23 = __floats2half2_rn(GSU > 2 ? acc[2] : 0.f,
                                            GSU > 3 ? acc[GSU - 1] : 0.f);
            uint2 o;
            o.x = *(unsigned*)&a01;
            o.y = *(unsigned*)&a23;
            kvq[(size_t)sq * T4 + t] = o;
        } else {
            int okb = ((h * 3 + 1) * 3 + c) * PP + u * GSU;
            int ovb = ((h * 3 + 2) * 3 + c) * PP + u * GSU;
            float ak[GSU], av[GSU];
#pragma unroll
            for (int e = 0; e < GSU; ++e) { ak[e] = bq[okb + e]; av[e] = bq[ovb + e]; }
#pragma unroll
            for (int l = 0; l < L; ++l) {
                float xv = xw[l];
#pragma unroll
                for (int e = 0; e < GSU; ++e) {
                    ak[e] = fmaf(xv, w[(okb + e) * L + l], ak[e]);
                    av[e] = fmaf(xv, w[(ovb + e) * L + l], av[e]);
                }
            }
            __half2 k01 = __floats2half2_rn(ak[0], ak[1]);
            __half2 k23 = __floats2half2_rn(GSU > 2 ? ak[2] : 0.f,
                                            GSU > 3 ? ak[GSU - 1] : 0.f);
            __half2 v01 = __floats2half2_rn(av[0], av[1]);
            __half2 v23 = __floats2half2_rn(GSU > 2 ? av[2] : 0.f,
                                            GSU > 3 ? av[GSU - 1] : 0.f);
            uint4 o;
            o.x = *(unsigned*)&k01;
            o.y = *(unsigned*)&k23;
            o.z = *(unsigned*)&v01;
            o.w = *(unsigned*)&v23;
            kvv[(size_t)sq * T4 + t] = o;
        }
    }
}

// Phase 2: single-pass unnormalized softmax; one 16B load gives k AND v.
template<int P, int NH, int NWIN, int OFS, int GSU, int HPT>
__global__ __launch_bounds__(256)
void attn4_pk(const uint2* __restrict__ kvq, const uint4* __restrict__ kvv,
              const float* __restrict__ hw, float* __restrict__ out)
{
    constexpr int PP = P * P, NGP = PP / GSU;
    constexpr int NT = NWIN + 2, T4 = 4 * NT * NT, PAD = OFS - P;
    constexpr float SCL = (P == 2) ? 0.28867513459481287f : 0.19245008972987526f;
    constexpr float DD  = (P == 2) ? 0.6065306597126334f : 0.7165313105737893f; // exp(-1/P)
    float dpw[2 * P - 1];
    dpw[0] = 1.f;
#pragma unroll
    for (int k = 1; k < 2 * P - 1; ++k) dpw[k] = dpw[k - 1] * DD;

    const int slot = threadIdx.x;                       // 0..127
    const int hg = __builtin_amdgcn_readfirstlane((int)threadIdx.y);
    int wlin = blockIdx.x * 128 + slot;
    const bool active = wlin < 4 * NWIN * NWIN;
    int wsafe = active ? wlin : 0;
    int c = blockIdx.y;
    int bb = wsafe / (NWIN * NWIN); int rr = wsafe - bb * (NWIN * NWIN);
    int yy = rr / NWIN, xx = rr - yy * NWIN;
    int tbase = bb * NT * NT + yy * NT + xx;
    int tn[9];
#pragma unroll
    for (int di = 0; di < 3; ++di)
#pragma unroll
        for (int dj = 0; dj < 3; ++dj) tn[di * 3 + dj] = tbase + di * NT + dj;
    float oa[PP];
#pragma unroll
    for (int e = 0; e < PP; ++e) oa[e] = 0.f;
#pragma unroll 1
    for (int hi = 0; hi < HPT; ++hi) {
        int h = hg * HPT + hi;
        int sb = (h * 3 + c) * NGP;
        float q[PP];
#pragma unroll
        for (int u = 0; u < NGP; ++u) {
            float g4[4];
            unpack4h(kvq[(size_t)(sb + u) * T4 + tn[4]], g4);
#pragma unroll
            for (int e = 0; e < GSU; ++e) q[u * GSU + e] = g4[e];
        }
        float se = 0.f;
        float tmp[PP];
#pragma unroll
        for (int e = 0; e < PP; ++e) tmp[e] = 0.f;
#pragma unroll
        for (int j = 0; j < 9; ++j) {
            int di = j / 3, dj = j - di * 3;
            float vreg[PP];
            float s = 0.f;
#pragma unroll
            for (int u = 0; u < NGP; ++u) {
                float k4[4], v4[4];
                unpack8h(kvv[(size_t)(sb + u) * T4 + tn[j]], k4, v4);
#pragma unroll
                for (int e = 0; e < GSU; ++e) {
                    int Pp = u * GSU + e;
                    int i = Pp / P, jj = Pp - i * P;
                    int er = (di == 0) ? (P - 1 - i) : (di == 2 ? i : 0);
                    int ec = (dj == 0) ? (P - 1 - jj) : (dj == 2 ? jj : 0);
                    s = fmaf(q[Pp] * k4[e], dpw[er + ec], s);
                    vreg[Pp] = v4[e];
                }
            }
            float e2 = __expf(s * SCL);
            se += e2;
#pragma unroll
            for (int e = 0; e < PP; ++e) tmp[e] = fmaf(e2, vreg[e], tmp[e]);
        }
        float f = hw[h] * fastrcp(se);
#pragma unroll
        for (int e = 0; e < PP; ++e) oa[e] = fmaf(f, tmp[e], oa[e]);
    }
    __shared__ float s_part[128][PP];
    if (hg == 1) {
#pragma unroll
        for (int e = 0; e < PP; ++e) s_part[slot][e] = oa[e];
    }
    __syncthreads();
    if (hg == 0 && active) {
        float* ob = out + (bb * 3 + c) * 65536;
#pragma unroll
        for (int i = 0; i < P; ++i) {
            int r = yy * P + i - PAD;
            if (PAD && r < 0) continue;
#pragma unroll
            for (int jj = 0; jj < P; ++jj) {
                int col = xx * P + jj - PAD;
                if (PAD && col < 0) continue;
                int e = i * P + jj;
                ob[(r << 8) + col] = oa[e] + s_part[slot][e];
            }
        }
    }
}

// -------- conv0 (5x5, 9->3, pad 2) + final, source-split over y ------------
__global__ __launch_bounds__(384)
void conv_finalv3(const float* __restrict__ x, const float* __restrict__ x9,
                  const float* __restrict__ x6, const float* __restrict__ x3,
                  const float* __restrict__ cw, const float* __restrict__ cb,
                  const float* __restrict__ pmax, float* __restrict__ out)
{
    const int slot = threadIdx.x;                       // 0..127
    const int src = __builtin_amdgcn_readfirstlane((int)threadIdx.y);  // 0,1,2
    int bb = blockIdx.x >> 8;                           // 1024 blocks, 256/batch
    __shared__ float s_g;
    {
        int flat = threadIdx.y * 128 + slot;
        if (flat < 32) {                                // 128 partials per batch
            const float* pm = pmax + bb * 128 + flat * 4;
            float v = fmaxf(fmaxf(pm[0], pm[1]), fmaxf(pm[2], pm[3]));
#pragma unroll
            for (int off = 16; off > 0; off >>= 1)
                v = fmaxf(v, __shfl_down(v, off, 64));
            if (flat == 0) s_g = v;
        }
    }
    int pair = (blockIdx.x & 255) * 128 + slot;         // within batch
    int xp = (pair & 127) << 1, r = pair >> 7;
    float a[3][2];
#pragma unroll
    for (int oc = 0; oc < 3; ++oc) { a[oc][0] = 0.f; a[oc][1] = 0.f; }
    const float* bp = (src == 0 ? x9 : (src == 1 ? x6 : x3)) + bb * 196608;
#pragma unroll 1
    for (int c2 = 0; c2 < 3; ++c2) {
        const float* pl = bp + c2 * 65536;
        const float* wp = cw + (src * 3 + c2) * 25;     // wave-uniform -> s_load
#pragma unroll
        for (int ky = 0; ky < 5; ++ky) {
            int rr = r + ky - 2;
            if ((unsigned)rr >= 256u) continue;
            const float* row = pl + (rr << 8);
            float2 va = (xp >= 2) ? *(const float2*)(row + xp - 2)
                                  : make_float2(0.f, 0.f);
            float2 vb = *(const float2*)(row + xp);
            float2 vc = (xp + 2 < 256) ? *(const float2*)(row + xp + 2)
                                       : make_float2(0.f, 0.f);
            float cv[6] = {va.x, va.y, vb.x, vb.y, vc.x, vc.y};
#pragma unroll
            for (int kx = 0; kx < 5; ++kx) {
                float w0 = wp[ky * 5 + kx];
                float w1 = wp[225 + ky * 5 + kx];
                float w2 = wp[450 + ky * 5 + kx];
                float v0 = cv[kx], v1 = cv[kx + 1];
                a[0][0] = fmaf(v0, w0, a[0][0]); a[0][1] = fmaf(v1, w0, a[0][1]);
                a[1][0] = fmaf(v0, w1, a[1][0]); a[1][1] = fmaf(v1, w1, a[1][1]);
                a[2][0] = fmaf(v0, w2, a[2][0]); a[2][1] = fmaf(v1, w2, a[2][1]);
            }
        }
    }
    __shared__ float s_part[2][128][6];
    if (src > 0) {
#pragma unroll
        for (int oc = 0; oc < 3; ++oc) {
            s_part[src - 1][slot][oc * 2]     = a[oc][0];
            s_part[src - 1][slot][oc * 2 + 1] = a[oc][1];
        }
    }
    __syncthreads();
    if (src == 0) {
        float g = s_g;
        int pix = (r << 8) + xp;
        const float* xb = x + bb * 196608;
        float* ob = out + bb * 196608;
#pragma unroll
        for (int oc = 0; oc < 3; ++oc) {
            float a0 = a[oc][0] + s_part[0][slot][oc * 2] + s_part[1][slot][oc * 2] + cb[oc];
            float a1 = a[oc][1] + s_part[0][slot][oc * 2 + 1] + s_part[1][slot][oc * 2 + 1] + cb[oc];
            float2 xv = *(const float2*)(xb + oc * 65536 + pix);
            float2 o2;
            float x0;
            x0 = fmaxf(a0, 0.f); o2.x = fmaxf(xv.x * x0 + g - x0, 0.f);
            x0 = fmaxf(a1, 0.f); o2.y = fmaxf(xv.y * x0 + g - x0, 0.f);
            *(float2*)(ob + oc * 65536 + pix) = o2;
        }
    }
}

extern "C" void kernel_launch(void* const* d_in, const int* in_sizes, int n_in,
                              void* d_out, int out_size, void* d_ws, size_t ws_size,
                              hipStream_t stream)
{
    const float* x   = (const float*)d_in[0];
    const float* w3  = (const float*)d_in[1];
    const float* b3  = (const float*)d_in[2];
    const float* hw3 = (const float*)d_in[3];
    const float* w6  = (const float*)d_in[4];
    const float* b6  = (const float*)d_in[5];
    const float* hw6 = (const float*)d_in[6];
    const float* w9  = (const float*)d_in[7];
    const float* b9  = (const float*)d_in[8];
    const float* hw9 = (const float*)d_in[9];
    const float* cw  = (const float*)d_in[10];
    const float* cb  = (const float*)d_in[11];

    float* ws   = (float*)d_ws;
    float* x3b  = ws;                     // 786432 floats
    float* x6b  = ws + 786432;            // 786432
    float* x9b  = ws + 1572864;           // 786432
    float* pmax = ws + 2359296;           // 512
    uint2* kvq  = (uint2*)(ws + 2360320); // q slots: <= 12*67600*8 B = 6.5 MB
    uint4* kvv  = (uint4*)(ws + 3982720); // k|v slots: <= 12*67600*16 B = 13 MB
    float* out  = (float*)d_out;

    // stage 1 (p=1), 2x2 quads, 2-way head split, + fused batch-max partials
    attn_p1q<<<512, dim3(128, 2), 0, stream>>>(x, w3, b3, hw3, x3b, pmax);

    // stage 2: p=2, NH=4, NWIN=128, OFS=2, GSU=4 (NGP=1), NCH=6
    proj4_pk<2, 4, 128, 2, 4, 6><<<1057, dim3(64, 6), 0, stream>>>(x3b, w6, b6, kvq, kvv);
    attn4_pk<2, 4, 128, 2, 4, 2><<<dim3(512, 3), dim3(128, 2), 0, stream>>>(kvq, kvv, hw6, x6b);
    // stage 3: p=3, NH=2, NWIN=86, OFS=5, GSU=3 (NGP=3), NCH=9
    proj4_pk<3, 2, 86, 5, 3, 9><<<484, dim3(64, 9), 0, stream>>>(x6b, w9, b9, kvq, kvv);
    attn4_pk<3, 2, 86, 5, 3, 1><<<dim3(232, 3), dim3(128, 2), 0, stream>>>(kvq, kvv, hw9, x9b);

    conv_finalv3<<<1024, dim3(128, 3), 0, stream>>>(x, x9b, x6b, x3b, cw, cb, pmax, out);
}